// Round 3
// baseline (6940.188 us; speedup 1.0000x reference)
//
#include <hip/hip_runtime.h>
#include <math.h>

#define AGENT __HIP_MEMORY_SCOPE_AGENT

constexpr int kNWG   = 32;
constexpr int kTPB   = 256;
constexpr int kD     = 16;    // data dim
constexpr int kH     = 128;   // hidden dim
constexpr int kW     = 256;   // vf mlp width
constexpr int kOut   = 2048;  // D*H
constexpr int kLsig  = 137;
constexpr int kT     = 200001;
constexpr int kNRow  = 101;   // distinct eval times
constexpr int kNEval = 200;

// workspace layout (float indices) — flags FIRST; total 13216 floats (~53 KB)
constexpr int FLAGS_OFF = 0;      // 32 uints
constexpr int IDX_OFF   = 32;     // 101 ints
constexpr int INV_OFF   = 160;    // 101 floats
constexpr int YB_OFF    = 288;    // 128
constexpr int H1B_OFF   = 416;    // 256
constexpr int H2B_OFF   = 672;    // 256
constexpr int WB_OFF    = 928;    // 2048
constexpr int T1B_OFF   = 2976;   // 4096
constexpr int T2B_OFF   = 7072;   // 4096
constexpr int RSP_OFF   = 11168;  // 2048

__device__ __forceinline__ float b2f(unsigned short u){
  union { unsigned int i; float f; } v; v.i = ((unsigned int)u) << 16; return v.f;
}
__device__ __forceinline__ unsigned short f2b(float f){ // RNE
  unsigned int x = __float_as_uint(f);
  unsigned int r = x + 0x7fffu + ((x >> 16) & 1u);
  return (unsigned short)(r >> 16);
}
// dtype-dispatched element load: element i of a buffer that is fp32 or bf16
__device__ __forceinline__ float ldf(const void* p, size_t i, bool bf){
  return bf ? b2f(((const unsigned short*)p)[i]) : ((const float*)p)[i];
}
__device__ __forceinline__ float aload(const float* p){
  return __hip_atomic_load(p, __ATOMIC_RELAXED, AGENT);
}
__device__ __forceinline__ void astore(float* p, float v){
  __hip_atomic_store(p, v, __ATOMIC_RELAXED, AGENT);
}
__device__ __forceinline__ int pairidx(int i, int j){ // i<j, triu_indices(16,1) row-major
  return i*15 - (i*(i-1))/2 + (j - i - 1);
}

// software inter-WG barrier: per-WG flag slots, release store + acquire poll.
__device__ __forceinline__ void gbar(unsigned* flags, int g, unsigned epoch, int tid){
  __threadfence();            // drain this thread's global stores
  __syncthreads();            // whole WG drained
  if (tid == 0)
    __hip_atomic_store(&flags[g], epoch, __ATOMIC_RELEASE, AGENT);
  if (tid < kNWG){
    int spins = 0;
    while (__hip_atomic_load(&flags[tid], __ATOMIC_ACQUIRE, AGENT) < epoch){
      __builtin_amdgcn_s_sleep(2);
      if (++spins > (1 << 22)) break;   // session-safety bailout; never hit when healthy
    }
  }
  __syncthreads();
}

// ---------------- init: t-chain, exact searchsorted, idx/inv table, y0, flags ----------------
__global__ void cde_init(const void* __restrict__ tsp, const void* __restrict__ x0p,
                         const void* __restrict__ l1wp, const void* __restrict__ l1bp,
                         float* __restrict__ ws)
{
  const int tid = threadIdx.x; // 128 threads
  const bool bf = (((const unsigned*)tsp)[0] != 0u);  // fp32 ts[0]==0.0f -> word0==0
  const float ts0 = ldf(tsp, 0, bf);
  const float dt  = (ldf(tsp, kT-1, bf) - ts0) / 100.0f;  // fp32, same as reference

  if (tid < kNWG) ((unsigned*)(ws + FLAGS_OFF))[tid] = 0u;

  if (tid < kNRow){
    // exact fp32 left-to-right accumulation, matching the reference scan carry
    float t = ts0;
    for (int i = 0; i < tid; i++) t += dt;
    // searchsorted(side=left) over ts[1:]: first pos with a[pos] >= t
    const int N1 = kT - 1;
    int lo = 0, hi = N1;
    while (lo < hi){
      int mid = (lo + hi) >> 1;
      if (ldf(tsp, 1 + mid, bf) < t) lo = mid + 1; else hi = mid;
    }
    int idx = lo + 1; if (idx > kT-1) idx = kT-1; if (idx < 1) idx = 1;
    ((int*)ws)[IDX_OFF + tid] = idx;
    float w = ldf(tsp, idx, bf) - ldf(tsp, idx-1, bf);
    ws[INV_OFF + tid] = (w > 0.f) ? (1.0f / w) : 0.f;
  }
  if (tid < kH){
    float acc = ldf(l1bp, tid, bf);
    for (int d2 = 0; d2 < kD; d2++) acc += ldf(x0p, d2, bf) * ldf(l1wp, d2*kH + tid, bf);
    ws[YB_OFF + tid] = acc;   // y0 = x0 @ l1_w + l1_b
  }
}

// ---------------- persistent main kernel ----------------
struct SMem {
  float w3T[64][257];   // w3 cols g*64..+63, transposed, padded   (~64.2 KB)
  float w1cT[8][129];   // w1[:, g*8+o] transposed, padded
  float w2cT[8][257];
  float Wt[kD][129];    // full W = tanh(z3), padded
  float T1[kD][257];    // full T1s, padded
  float h1[kW], h2[kW];
  float ls[kLsig + 7];
  float y[kH], ymid[kH], k1v[kH];
  float Urow[kW];
  float red[4][64];
  float tanhp[64];
  float s1p[8], s2p[8], b1c[8], b2c[8];
  float b3c[64];
  float Acol[kD];
  float lgts[16];
};
static_assert(sizeof(SMem) <= 120*1024, "LDS budget");

__global__ __launch_bounds__(kTPB, 1)
void cde_main(const void* __restrict__ tsp, const void* __restrict__ logsigp,
              const void* __restrict__ w1p, const void* __restrict__ b1p,
              const void* __restrict__ w2p, const void* __restrict__ b2p,
              const void* __restrict__ w3p, const void* __restrict__ b3p,
              const void* __restrict__ l2wp, const void* __restrict__ l2bp,
              float* __restrict__ ws, void* __restrict__ outp)
{
  __shared__ SMem s;
  const int g = blockIdx.x, tid = threadIdx.x;
  const int lane = tid & 63, wave = tid >> 6;
  const bool bf = (((const unsigned*)tsp)[0] != 0u);
  unsigned* flags = (unsigned*)(ws + FLAGS_OFF);
  float* h1b = ws + H1B_OFF;  float* h2b = ws + H2B_OFF;
  float* Wb  = ws + WB_OFF;   float* T1b = ws + T1B_OFF;
  float* T2b = ws + T2B_OFF;  float* rsp = ws + RSP_OFF;

  // ---- stage weights into LDS (one-time) ----
  for (int i = tid; i < 8*kH; i += kTPB){ int o = i>>7, j = i&127; s.w1cT[o][j] = ldf(w1p, (size_t)j*kW + g*8 + o, bf); }
  for (int i = tid; i < 8*kW; i += kTPB){ int o = i>>8, n = i&255; s.w2cT[o][n] = ldf(w2p, (size_t)n*kW + g*8 + o, bf); }
  for (int i = tid; i < 64*kW; i += kTPB){ int n = i>>6, c = i&63;  s.w3T[c][n]  = ldf(w3p, (size_t)n*kOut + g*64 + c, bf); }
  if (tid < 8){ s.b1c[tid] = ldf(b1p, g*8 + tid, bf); s.b2c[tid] = ldf(b2p, g*8 + tid, bf); }
  if (tid < 64) s.b3c[tid] = ldf(b3p, g*64 + tid, bf);
  if (tid < kH) s.y[tid] = ws[YB_OFF + tid];
  const float dt  = (ldf(tsp, kT-1, bf) - ldf(tsp, 0, bf)) / 100.0f;
  const float dth = 0.5f * dt;
  __syncthreads();

  unsigned epoch = 0;

  for (int e = 0; e < kNEval; e++){
    const int r = (e + 1) >> 1;            // e=2s -> t_s, e=2s+1 -> t_{s+1}
    {
      const int idx = ((const int*)ws)[IDX_OFF + r];
      const float inv = ws[INV_OFF + r];
      for (int c = tid; c < kLsig; c += kTPB)
        s.ls[c] = ldf(logsigp, (size_t)(idx - 1)*kLsig + c, bf) * inv;  // fold 1/width
    }
    __syncthreads();
    const float* ycur = (e & 1) ? s.ymid : s.y;

    // ---- G1: z1[n] for this WG's 8 cols; h1 -> bcast, silu' local ----
    {
      const int o = tid >> 5, l = tid & 31;
      float acc = 0.f;
      #pragma unroll
      for (int jj = 0; jj < 4; jj++){ int j = jj*32 + l; acc += ycur[j] * s.w1cT[o][j]; }
      #pragma unroll
      for (int off = 16; off; off >>= 1) acc += __shfl_down(acc, off, 32);
      if (l == 0){
        float z = acc + s.b1c[o];
        float sg = 1.0f / (1.0f + expf(-z));
        s.s1p[o] = sg * (1.0f + z*(1.0f - sg));
        astore(h1b + g*8 + o, z * sg);
      }
    }
    gbar(flags, g, ++epoch, tid);
    s.h1[tid] = aload(h1b + tid);
    __syncthreads();

    // ---- G2: z2[n'] ----
    {
      const int o = tid >> 5, l = tid & 31;
      float acc = 0.f;
      #pragma unroll
      for (int jj = 0; jj < 8; jj++){ int j = jj*32 + l; acc += s.h1[j] * s.w2cT[o][j]; }
      #pragma unroll
      for (int off = 16; off; off >>= 1) acc += __shfl_down(acc, off, 32);
      if (l == 0){
        float z = acc + s.b2c[o];
        float sg = 1.0f / (1.0f + expf(-z));
        s.s2p[o] = sg * (1.0f + z*(1.0f - sg));
        astore(h2b + g*8 + o, z * sg);
      }
    }
    gbar(flags, g, ++epoch, tid);
    s.h2[tid] = aload(h2b + tid);
    __syncthreads();

    // ---- G3: z3 for 64 owned cols from LDS w3T; W=tanh bcast ----
    {
      float acc = 0.f;
      #pragma unroll 8
      for (int j = 0; j < 64; j++) acc += s.h2[wave*64 + j] * s.w3T[lane][wave*64 + j];
      s.red[wave][lane] = acc;
    }
    __syncthreads();
    if (wave == 0){
      float z3 = s.red[0][lane] + s.red[1][lane] + s.red[2][lane] + s.red[3][lane] + s.b3c[lane];
      float Wv = tanhf(z3);
      s.tanhp[lane] = 1.0f - Wv*Wv;
      astore(Wb + g*64 + lane, Wv);
    }
    gbar(flags, g, ++epoch, tid);
    for (int i = tid; i < kD*kH; i += kTPB){ int k = i>>7, h = i&127; s.Wt[k][h] = aload(Wb + i); }
    __syncthreads();

    // ---- G4: T1s[k][n] = s1'[n] * (W_k @ w1)[n], n in owned 8 cols ----
    {
      const int outi = tid >> 1, half = tid & 1;
      const int k = outi >> 3, o = outi & 7;
      float acc = 0.f;
      #pragma unroll
      for (int jj = 0; jj < 64; jj++){ int j = jj*2 + half; acc += s.Wt[k][j] * s.w1cT[o][j]; }
      acc += __shfl_xor(acc, 1);
      if (half == 0) astore(T1b + k*kW + g*8 + o, acc * s.s1p[o]);
    }
    gbar(flags, g, ++epoch, tid);
    for (int i = tid; i < kD*kW; i += kTPB){ int k = i>>8, n = i&255; s.T1[k][n] = aload(T1b + i); }
    __syncthreads();

    // ---- G5: T2s[k][n'] = s2'[n'] * (T1s[k] @ w2)[n'] ----
    {
      const int outi = tid >> 1, half = tid & 1;
      const int k = outi >> 3, o = outi & 7;
      float acc = 0.f;
      #pragma unroll 16
      for (int jj = 0; jj < 128; jj++){ int n = jj*2 + half; acc += s.T1[k][n] * s.w2cT[o][n]; }
      acc += __shfl_xor(acc, 1);
      if (half == 0) astore(T2b + k*kW + g*8 + o, acc * s.s2p[o]);
    }
    gbar(flags, g, ++epoch, tid);

    // ---- G6: U row for block i = g>>1; bracket (+ linear for g<2) via LDS w3T ----
    if (tid < kD){
      const int ig = g >> 1; const int k = tid; float v = 0.f;
      if (k < ig)      v =  s.ls[17 + pairidx(k, ig)];
      else if (k > ig) v = -s.ls[17 + pairidx(ig, k)];
      s.Acol[k] = v;
    }
    __syncthreads();
    {
      float u = 0.f; const int n = tid;
      #pragma unroll
      for (int k2 = 0; k2 < kD; k2++) u += s.Acol[k2] * aload(T2b + k2*kW + n);
      s.Urow[n] = u;
    }
    __syncthreads();
    {
      float acc = 0.f;
      #pragma unroll 8
      for (int j = 0; j < 64; j++) acc += s.Urow[wave*64 + j] * s.w3T[lane][wave*64 + j];
      s.red[wave][lane] = acc;
    }
    __syncthreads();
    if (wave == 0){
      float v = (s.red[0][lane] + s.red[1][lane] + s.red[2][lane] + s.red[3][lane]) * s.tanhp[lane];
      if (g < 2){   // block i=0 owners add the linear term ls1 @ W for their h-half
        float lin = 0.f; const int h = g*64 + lane;
        #pragma unroll
        for (int k2 = 0; k2 < kD; k2++) lin += s.ls[1 + k2] * s.Wt[k2][h];
        v += lin;
      }
      astore(rsp + g*64 + lane, v);
    }
    gbar(flags, g, ++epoch, tid);

    // ---- G7: reduce res partials, Heun update (redundant in every WG) ----
    if (tid < kH){
      const int hh = tid >> 6, hl = tid & 63;
      float rs = 0.f;
      #pragma unroll
      for (int i2 = 0; i2 < kD; i2++) rs += aload(rsp + (2*i2 + hh)*64 + hl);
      if (!(e & 1)){ s.k1v[tid] = rs; s.ymid[tid] = s.y[tid] + dt * rs; }
      else         { s.y[tid] = s.y[tid] + dth * (s.k1v[tid] + rs); }
    }
    __syncthreads();
  }

  // ---- classification head + softmax (WG0), dtype-matched output ----
  if (g == 0){
    if (tid < 10){
      float acc = ldf(l2bp, tid, bf);
      for (int h = 0; h < kH; h++) acc += s.y[h] * ldf(l2wp, (size_t)h*10 + tid, bf);
      s.lgts[tid] = acc;
    }
    __syncthreads();
    if (tid < 10){
      float m = s.lgts[0];
      #pragma unroll
      for (int i2 = 1; i2 < 10; i2++) m = fmaxf(m, s.lgts[i2]);
      float num = expf(s.lgts[tid] - m);
      float den = 0.f;
      #pragma unroll
      for (int i2 = 0; i2 < 10; i2++) den += expf(s.lgts[i2] - m);
      float v = num / den;
      if (bf) ((unsigned short*)outp)[tid] = f2b(v);
      else    ((float*)outp)[tid] = v;
    }
  }
}

extern "C" void kernel_launch(void* const* d_in, const int* in_sizes, int n_in,
                              void* d_out, int out_size, void* d_ws, size_t ws_size,
                              hipStream_t stream)
{
  const void* ts   = d_in[0];
  const void* lsig = d_in[1];
  const void* x0   = d_in[2];
  // d_in[3] = intervals == ts
  const void* l1w  = d_in[4];
  const void* l1b  = d_in[5];
  const void* w1   = d_in[6];
  const void* b1   = d_in[7];
  const void* w2   = d_in[8];
  const void* b2   = d_in[9];
  const void* w3   = d_in[10];
  const void* b3   = d_in[11];
  const void* l2w  = d_in[12];
  const void* l2b  = d_in[13];
  float* ws = (float*)d_ws;

  hipLaunchKernelGGL(cde_init, dim3(1), dim3(128), 0, stream, ts, x0, l1w, l1b, ws);
  hipLaunchKernelGGL(cde_main, dim3(kNWG), dim3(kTPB), 0, stream,
                     ts, lsig, w1, b1, w2, b2, w3, b3, l2w, l2b, ws, d_out);
}

// Round 4
// 4756.251 us; speedup vs baseline: 1.4592x; 1.4592x over previous
//
#include <hip/hip_runtime.h>
#include <math.h>

#define AGENT __HIP_MEMORY_SCOPE_AGENT

constexpr int kNWG   = 32;
constexpr int kTPB   = 256;
constexpr int kD     = 16;    // data dim
constexpr int kH     = 128;   // hidden dim
constexpr int kW     = 256;   // vf mlp width
constexpr int kOut   = 2048;  // D*H
constexpr int kLsig  = 137;
constexpr int kT     = 200001;
constexpr int kNRow  = 101;   // distinct eval times
constexpr int kNEval = 200;

// workspace layout (float indices) — flags FIRST; total 13216 floats (~53 KB)
constexpr int FLAGS_OFF = 0;      // 32 uints
constexpr int IDX_OFF   = 32;     // 101 ints
constexpr int INV_OFF   = 160;    // 101 floats
constexpr int YB_OFF    = 288;    // 128
constexpr int H1B_OFF   = 416;    // 256
constexpr int H2B_OFF   = 672;    // 256
constexpr int WB_OFF    = 928;    // 2048
constexpr int T1B_OFF   = 2976;   // 4096
constexpr int T2B_OFF   = 7072;   // 4096
constexpr int RSP_OFF   = 11168;  // 2048

__device__ __forceinline__ float b2f(unsigned short u){
  union { unsigned int i; float f; } v; v.i = ((unsigned int)u) << 16; return v.f;
}
__device__ __forceinline__ unsigned short f2b(float f){ // RNE
  unsigned int x = __float_as_uint(f);
  unsigned int r = x + 0x7fffu + ((x >> 16) & 1u);
  return (unsigned short)(r >> 16);
}
// dtype-dispatched element load: element i of a buffer that is fp32 or bf16
__device__ __forceinline__ float ldf(const void* p, size_t i, bool bf){
  return bf ? b2f(((const unsigned short*)p)[i]) : ((const float*)p)[i];
}
// cross-WG data plane: AGENT-scope relaxed atomics — these bypass the
// non-coherent per-XCD L2 (sc-bit accesses) and are coherent at the IF$.
__device__ __forceinline__ float aload(const float* p){
  return __hip_atomic_load(p, __ATOMIC_RELAXED, AGENT);
}
__device__ __forceinline__ void astore(float* p, float v){
  __hip_atomic_store(p, v, __ATOMIC_RELAXED, AGENT);
}
__device__ __forceinline__ int pairidx(int i, int j){ // i<j, triu_indices(16,1) row-major
  return i*15 - (i*(i-1))/2 + (j - i - 1);
}

// software inter-WG barrier, NO cache maintenance:
//  - all cross-WG payloads are sc-bit (AGENT) accesses, so no wbl2/inv needed
//  - ordering: drain stores (vmcnt0 via explicit wait + __syncthreads), then
//    relaxed flag store; consumers poll with relaxed loads.
__device__ __forceinline__ void gbar(unsigned* flags, int g, unsigned epoch, int tid){
  asm volatile("s_waitcnt vmcnt(0)" ::: "memory");  // my payload stores acked at IF$
  __syncthreads();                                  // whole WG drained
  if (tid == 0)
    __hip_atomic_store(&flags[g], epoch, __ATOMIC_RELAXED, AGENT);
  if (tid < kNWG){
    int spins = 0;
    while (__hip_atomic_load(&flags[tid], __ATOMIC_RELAXED, AGENT) < epoch){
      __builtin_amdgcn_s_sleep(1);
      if (++spins > (1 << 16)) break;   // session-safety bailout; never hit when healthy
    }
  }
  __syncthreads();
}

// ---------------- init: t-chain, exact searchsorted, idx/inv table, y0, flags ----------------
__global__ void cde_init(const void* __restrict__ tsp, const void* __restrict__ x0p,
                         const void* __restrict__ l1wp, const void* __restrict__ l1bp,
                         float* __restrict__ ws)
{
  const int tid = threadIdx.x; // 128 threads
  const bool bf = (((const unsigned*)tsp)[0] != 0u);  // fp32 ts[0]==0.0f -> word0==0
  const float ts0 = ldf(tsp, 0, bf);
  const float dt  = (ldf(tsp, kT-1, bf) - ts0) / 100.0f;  // fp32, same as reference

  if (tid < kNWG) ((unsigned*)(ws + FLAGS_OFF))[tid] = 0u;

  if (tid < kNRow){
    // exact fp32 left-to-right accumulation, matching the reference scan carry
    float t = ts0;
    for (int i = 0; i < tid; i++) t += dt;
    // searchsorted(side=left) over ts[1:]: first pos with a[pos] >= t
    const int N1 = kT - 1;
    int lo = 0, hi = N1;
    while (lo < hi){
      int mid = (lo + hi) >> 1;
      if (ldf(tsp, 1 + mid, bf) < t) lo = mid + 1; else hi = mid;
    }
    int idx = lo + 1; if (idx > kT-1) idx = kT-1; if (idx < 1) idx = 1;
    ((int*)ws)[IDX_OFF + tid] = idx;
    float w = ldf(tsp, idx, bf) - ldf(tsp, idx-1, bf);
    ws[INV_OFF + tid] = (w > 0.f) ? (1.0f / w) : 0.f;
  }
  if (tid < kH){
    float acc = ldf(l1bp, tid, bf);
    for (int d2 = 0; d2 < kD; d2++) acc += ldf(x0p, d2, bf) * ldf(l1wp, d2*kH + tid, bf);
    ws[YB_OFF + tid] = acc;   // y0 = x0 @ l1_w + l1_b
  }
}

// ---------------- persistent main kernel ----------------
struct SMem {
  float w3T[64][257];   // w3 cols g*64..+63, transposed, padded   (~64.2 KB)
  float w1cT[8][129];   // w1[:, g*8+o] transposed, padded
  float w2cT[8][257];
  float Wt[kD][129];    // full W = tanh(z3), padded
  float T1[kD][257];    // full T1s, padded
  float h1[kW], h2[kW];
  float ls[kLsig + 7];
  float y[kH], ymid[kH], k1v[kH];
  float Urow[kW];
  float red[4][64];
  float tanhp[64];
  float s1p[8], s2p[8], b1c[8], b2c[8];
  float b3c[64];
  float Acol[kD];
  float lgts[16];
};
static_assert(sizeof(SMem) <= 120*1024, "LDS budget");

__global__ __launch_bounds__(kTPB, 1)
void cde_main(const void* __restrict__ tsp, const void* __restrict__ logsigp,
              const void* __restrict__ w1p, const void* __restrict__ b1p,
              const void* __restrict__ w2p, const void* __restrict__ b2p,
              const void* __restrict__ w3p, const void* __restrict__ b3p,
              const void* __restrict__ l2wp, const void* __restrict__ l2bp,
              float* __restrict__ ws, void* __restrict__ outp)
{
  __shared__ SMem s;
  const int g = blockIdx.x, tid = threadIdx.x;
  const int lane = tid & 63, wave = tid >> 6;
  const bool bf = (((const unsigned*)tsp)[0] != 0u);
  unsigned* flags = (unsigned*)(ws + FLAGS_OFF);
  float* h1b = ws + H1B_OFF;  float* h2b = ws + H2B_OFF;
  float* Wb  = ws + WB_OFF;   float* T1b = ws + T1B_OFF;
  float* T2b = ws + T2B_OFF;  float* rsp = ws + RSP_OFF;

  // ---- stage weights into LDS (one-time) ----
  for (int i = tid; i < 8*kH; i += kTPB){ int o = i>>7, j = i&127; s.w1cT[o][j] = ldf(w1p, (size_t)j*kW + g*8 + o, bf); }
  for (int i = tid; i < 8*kW; i += kTPB){ int o = i>>8, n = i&255; s.w2cT[o][n] = ldf(w2p, (size_t)n*kW + g*8 + o, bf); }
  for (int i = tid; i < 64*kW; i += kTPB){ int n = i>>6, c = i&63;  s.w3T[c][n]  = ldf(w3p, (size_t)n*kOut + g*64 + c, bf); }
  if (tid < 8){ s.b1c[tid] = ldf(b1p, g*8 + tid, bf); s.b2c[tid] = ldf(b2p, g*8 + tid, bf); }
  if (tid < 64) s.b3c[tid] = ldf(b3p, g*64 + tid, bf);
  if (tid < kH) s.y[tid] = ws[YB_OFF + tid];
  const float dt  = (ldf(tsp, kT-1, bf) - ldf(tsp, 0, bf)) / 100.0f;
  const float dth = 0.5f * dt;
  __syncthreads();

  unsigned epoch = 0;

  for (int e = 0; e < kNEval; e++){
    const int r = (e + 1) >> 1;            // e=2s -> t_s, e=2s+1 -> t_{s+1}
    {
      const int idx = ((const int*)ws)[IDX_OFF + r];
      const float inv = ws[INV_OFF + r];
      for (int c = tid; c < kLsig; c += kTPB)
        s.ls[c] = ldf(logsigp, (size_t)(idx - 1)*kLsig + c, bf) * inv;  // fold 1/width
    }
    __syncthreads();
    const float* ycur = (e & 1) ? s.ymid : s.y;

    // ---- G1: z1[n] for this WG's 8 cols; h1 -> bcast, silu' local ----
    {
      const int o = tid >> 5, l = tid & 31;
      float acc = 0.f;
      #pragma unroll
      for (int jj = 0; jj < 4; jj++){ int j = jj*32 + l; acc += ycur[j] * s.w1cT[o][j]; }
      #pragma unroll
      for (int off = 16; off; off >>= 1) acc += __shfl_down(acc, off, 32);
      if (l == 0){
        float z = acc + s.b1c[o];
        float sg = 1.0f / (1.0f + expf(-z));
        s.s1p[o] = sg * (1.0f + z*(1.0f - sg));
        astore(h1b + g*8 + o, z * sg);
      }
    }
    gbar(flags, g, ++epoch, tid);
    s.h1[tid] = aload(h1b + tid);
    __syncthreads();

    // ---- G2: z2[n'] ----
    {
      const int o = tid >> 5, l = tid & 31;
      float acc = 0.f;
      #pragma unroll
      for (int jj = 0; jj < 8; jj++){ int j = jj*32 + l; acc += s.h1[j] * s.w2cT[o][j]; }
      #pragma unroll
      for (int off = 16; off; off >>= 1) acc += __shfl_down(acc, off, 32);
      if (l == 0){
        float z = acc + s.b2c[o];
        float sg = 1.0f / (1.0f + expf(-z));
        s.s2p[o] = sg * (1.0f + z*(1.0f - sg));
        astore(h2b + g*8 + o, z * sg);
      }
    }
    gbar(flags, g, ++epoch, tid);
    s.h2[tid] = aload(h2b + tid);
    __syncthreads();

    // ---- G3: z3 for 64 owned cols from LDS w3T; W=tanh bcast ----
    {
      float acc = 0.f;
      #pragma unroll 8
      for (int j = 0; j < 64; j++) acc += s.h2[wave*64 + j] * s.w3T[lane][wave*64 + j];
      s.red[wave][lane] = acc;
    }
    __syncthreads();
    if (wave == 0){
      float z3 = s.red[0][lane] + s.red[1][lane] + s.red[2][lane] + s.red[3][lane] + s.b3c[lane];
      float Wv = tanhf(z3);
      s.tanhp[lane] = 1.0f - Wv*Wv;
      astore(Wb + g*64 + lane, Wv);
    }
    gbar(flags, g, ++epoch, tid);
    for (int i = tid; i < kD*kH; i += kTPB){ int k = i>>7, h = i&127; s.Wt[k][h] = aload(Wb + i); }
    __syncthreads();

    // ---- G4: T1s[k][n] = s1'[n] * (W_k @ w1)[n], n in owned 8 cols ----
    {
      const int outi = tid >> 1, half = tid & 1;
      const int k = outi >> 3, o = outi & 7;
      float acc = 0.f;
      #pragma unroll
      for (int jj = 0; jj < 64; jj++){ int j = jj*2 + half; acc += s.Wt[k][j] * s.w1cT[o][j]; }
      acc += __shfl_xor(acc, 1);
      if (half == 0) astore(T1b + k*kW + g*8 + o, acc * s.s1p[o]);
    }
    gbar(flags, g, ++epoch, tid);
    for (int i = tid; i < kD*kW; i += kTPB){ int k = i>>8, n = i&255; s.T1[k][n] = aload(T1b + i); }
    __syncthreads();

    // ---- G5: T2s[k][n'] = s2'[n'] * (T1s[k] @ w2)[n'] ----
    {
      const int outi = tid >> 1, half = tid & 1;
      const int k = outi >> 3, o = outi & 7;
      float acc = 0.f;
      #pragma unroll 16
      for (int jj = 0; jj < 128; jj++){ int n = jj*2 + half; acc += s.T1[k][n] * s.w2cT[o][n]; }
      acc += __shfl_xor(acc, 1);
      if (half == 0) astore(T2b + k*kW + g*8 + o, acc * s.s2p[o]);
    }
    gbar(flags, g, ++epoch, tid);

    // ---- G6: U row for block i = g>>1; bracket (+ linear for g<2) via LDS w3T ----
    if (tid < kD){
      const int ig = g >> 1; const int k = tid; float v = 0.f;
      if (k < ig)      v =  s.ls[17 + pairidx(k, ig)];
      else if (k > ig) v = -s.ls[17 + pairidx(ig, k)];
      s.Acol[k] = v;
    }
    __syncthreads();
    {
      float u = 0.f; const int n = tid;
      #pragma unroll
      for (int k2 = 0; k2 < kD; k2++) u += s.Acol[k2] * aload(T2b + k2*kW + n);
      s.Urow[n] = u;
    }
    __syncthreads();
    {
      float acc = 0.f;
      #pragma unroll 8
      for (int j = 0; j < 64; j++) acc += s.Urow[wave*64 + j] * s.w3T[lane][wave*64 + j];
      s.red[wave][lane] = acc;
    }
    __syncthreads();
    if (wave == 0){
      float v = (s.red[0][lane] + s.red[1][lane] + s.red[2][lane] + s.red[3][lane]) * s.tanhp[lane];
      if (g < 2){   // block i=0 owners add the linear term ls1 @ W for their h-half
        float lin = 0.f; const int h = g*64 + lane;
        #pragma unroll
        for (int k2 = 0; k2 < kD; k2++) lin += s.ls[1 + k2] * s.Wt[k2][h];
        v += lin;
      }
      astore(rsp + g*64 + lane, v);
    }
    gbar(flags, g, ++epoch, tid);

    // ---- G7: reduce res partials, Heun update (redundant in every WG) ----
    if (tid < kH){
      const int hh = tid >> 6, hl = tid & 63;
      float rs = 0.f;
      #pragma unroll
      for (int i2 = 0; i2 < kD; i2++) rs += aload(rsp + (2*i2 + hh)*64 + hl);
      if (!(e & 1)){ s.k1v[tid] = rs; s.ymid[tid] = s.y[tid] + dt * rs; }
      else         { s.y[tid] = s.y[tid] + dth * (s.k1v[tid] + rs); }
    }
    __syncthreads();
  }

  // ---- classification head + softmax (WG0), dtype-matched output ----
  if (g == 0){
    if (tid < 10){
      float acc = ldf(l2bp, tid, bf);
      for (int h = 0; h < kH; h++) acc += s.y[h] * ldf(l2wp, (size_t)h*10 + tid, bf);
      s.lgts[tid] = acc;
    }
    __syncthreads();
    if (tid < 10){
      float m = s.lgts[0];
      #pragma unroll
      for (int i2 = 1; i2 < 10; i2++) m = fmaxf(m, s.lgts[i2]);
      float num = expf(s.lgts[tid] - m);
      float den = 0.f;
      #pragma unroll
      for (int i2 = 0; i2 < 10; i2++) den += expf(s.lgts[i2] - m);
      float v = num / den;
      if (bf) ((unsigned short*)outp)[tid] = f2b(v);
      else    ((float*)outp)[tid] = v;
    }
  }
}

extern "C" void kernel_launch(void* const* d_in, const int* in_sizes, int n_in,
                              void* d_out, int out_size, void* d_ws, size_t ws_size,
                              hipStream_t stream)
{
  const void* ts   = d_in[0];
  const void* lsig = d_in[1];
  const void* x0   = d_in[2];
  // d_in[3] = intervals == ts
  const void* l1w  = d_in[4];
  const void* l1b  = d_in[5];
  const void* w1   = d_in[6];
  const void* b1   = d_in[7];
  const void* w2   = d_in[8];
  const void* b2   = d_in[9];
  const void* w3   = d_in[10];
  const void* b3   = d_in[11];
  const void* l2w  = d_in[12];
  const void* l2b  = d_in[13];
  float* ws = (float*)d_ws;

  hipLaunchKernelGGL(cde_init, dim3(1), dim3(128), 0, stream, ts, x0, l1w, l1b, ws);
  hipLaunchKernelGGL(cde_main, dim3(kNWG), dim3(kTPB), 0, stream,
                     ts, lsig, w1, b1, w2, b2, w3, b3, l2w, l2b, ws, d_out);
}